// Round 1
// baseline (777.697 us; speedup 1.0000x reference)
//
#include <hip/hip_runtime.h>
#include <hip/hip_bf16.h>
#include <cstdint>

typedef float f32x4 __attribute__((ext_vector_type(4)));
typedef __bf16 bf16x8 __attribute__((ext_vector_type(8)));

#define HID 128

// Pack W [K][128] fp32 -> fragment-major bf16: Bf[ki][nf][lane][8]
// lane l of fragment (ki,nf) holds B[k = ki*32 + (l>>4)*8 + j][n = nf*16 + (l&15)]
__global__ void pack_b_frag(const float* __restrict__ W, __bf16* __restrict__ Bf, int kiters) {
    int idx = blockIdx.x * 256 + threadIdx.x;
    int total = kiters * 512;           // kiters * 8 nf * 64 lanes
    if (idx >= total) return;
    int lane = idx & 63;
    int nf = (idx >> 6) & 7;
    int ki = idx >> 9;
    int n = nf * 16 + (lane & 15);
    int kb = ki * 32 + ((lane >> 4) * 8);
    bf16x8 v;
#pragma unroll
    for (int j = 0; j < 8; ++j) v[j] = (__bf16)W[(size_t)(kb + j) * HID + n];
    *reinterpret_cast<bf16x8*>(Bf + (size_t)idx * 8) = v;
}

// C[M][128] = A[M][K] @ B[K][128] (+bias, relu). Block = 256 thr = 4 waves.
// Each block owns 32 rows; wave w handles K-range [w*niter*32, (w+1)*niter*32).
// A is fp32, converted to bf16 in-register. B comes pre-packed fragment-major.
// Concat support: k < cols0 -> A0, else A1 (col k-cols0).
template<bool BIAS_RELU>
__global__ __launch_bounds__(256) void gemm_tile(
    const float* __restrict__ A0, int lda0, int cols0,
    const float* __restrict__ A1, int lda1,
    const __bf16* __restrict__ Bf,
    const float* __restrict__ bias,
    float* __restrict__ out,
    int niter)
{
    const int tid = threadIdx.x;
    const int lane = tid & 63;
    const int w = tid >> 6;
    const int row_base = blockIdx.x * 32;
    const int rif = lane & 15;
    const int kg = lane >> 4;

    f32x4 zero = {0.f, 0.f, 0.f, 0.f};
    f32x4 acc[2][8];
#pragma unroll
    for (int i = 0; i < 2; ++i)
#pragma unroll
        for (int j = 0; j < 8; ++j) acc[i][j] = zero;

    const bf16x8* __restrict__ BfV = reinterpret_cast<const bf16x8*>(Bf);
    const int kstart = w * (niter * 32);

#pragma unroll 2
    for (int it = 0; it < niter; ++it) {
        const int k0 = kstart + it * 32;
        const int kc = k0 + kg * 8;
        bf16x8 af[2];
#pragma unroll
        for (int mi = 0; mi < 2; ++mi) {
            const int row = row_base + mi * 16 + rif;
            const float* ap;
            if (kc < cols0) ap = A0 + (size_t)row * lda0 + kc;
            else            ap = A1 + (size_t)row * lda1 + (kc - cols0);
            float4 v0 = *reinterpret_cast<const float4*>(ap);
            float4 v1 = *reinterpret_cast<const float4*>(ap + 4);
            af[mi][0] = (__bf16)v0.x; af[mi][1] = (__bf16)v0.y;
            af[mi][2] = (__bf16)v0.z; af[mi][3] = (__bf16)v0.w;
            af[mi][4] = (__bf16)v1.x; af[mi][5] = (__bf16)v1.y;
            af[mi][6] = (__bf16)v1.z; af[mi][7] = (__bf16)v1.w;
        }
        const bf16x8* bp = BfV + (size_t)(k0 >> 5) * 512 + lane;
#pragma unroll
        for (int nf = 0; nf < 8; ++nf) {
            bf16x8 b = bp[nf * 64];
            acc[0][nf] = __builtin_amdgcn_mfma_f32_16x16x32_bf16(af[0], b, acc[0][nf], 0, 0, 0);
            acc[1][nf] = __builtin_amdgcn_mfma_f32_16x16x32_bf16(af[1], b, acc[1][nf], 0, 0, 0);
        }
    }

    // cross-wave K-split reduction in LDS
    __shared__ float red[4][32][HID];
#pragma unroll
    for (int mi = 0; mi < 2; ++mi)
#pragma unroll
        for (int nf = 0; nf < 8; ++nf)
#pragma unroll
            for (int j = 0; j < 4; ++j)
                red[w][mi * 16 + kg * 4 + j][nf * 16 + rif] = acc[mi][nf][j];
    __syncthreads();
#pragma unroll
    for (int p = 0; p < 16; ++p) {
        int idx = tid + p * 256;
        int r = idx >> 7, c = idx & 127;
        float v = red[0][r][c] + red[1][r][c] + red[2][r][c] + red[3][r][c];
        if (BIAS_RELU) v = fmaxf(v + bias[c], 0.f);
        out[(size_t)(row_base + r) * HID + c] = v;
    }
}

// h2[n][4] = y[n][128] @ W2[128][4] (fp32 vector; tiny)
__global__ void gemm_w2(const float* __restrict__ y, const float* __restrict__ W2,
                        float* __restrict__ h2, int n) {
    int i = blockIdx.x * 256 + threadIdx.x;
    if (i >= n) return;
    float a0 = 0, a1 = 0, a2 = 0, a3 = 0;
#pragma unroll 8
    for (int k = 0; k < HID; k += 4) {
        float4 v = *reinterpret_cast<const float4*>(y + (size_t)i * HID + k);
        const float* wp = W2 + k * 4;
        a0 += v.x * wp[0] + v.y * wp[4] + v.z * wp[8]  + v.w * wp[12];
        a1 += v.x * wp[1] + v.y * wp[5] + v.z * wp[9]  + v.w * wp[13];
        a2 += v.x * wp[2] + v.y * wp[6] + v.z * wp[10] + v.w * wp[14];
        a3 += v.x * wp[3] + v.y * wp[7] + v.z * wp[11] + v.w * wp[15];
    }
    float4 r = {a0, a1, a2, a3};
    *reinterpret_cast<float4*>(h2 + (size_t)i * 4) = r;
}

__global__ void count_dst(const int* __restrict__ dst, int* __restrict__ cnt, int E) {
    int e = blockIdx.x * 256 + threadIdx.x;
    if (e < E) atomicAdd(&cnt[dst[e]], 1);
}

// single-wave exclusive scan of cnt -> offs; dinv = rsqrt(cnt+1)  (self-loop)
__global__ void scan_wave(const int* __restrict__ cnt, int* __restrict__ offs,
                          float* __restrict__ dinv, int n) {
    int lane = threadIdx.x;
    int carry = 0;
    for (int base = 0; base < n; base += 64) {
        int i = base + lane;
        int v = (i < n) ? cnt[i] : 0;
        int s = v;
#pragma unroll
        for (int off = 1; off < 64; off <<= 1) {
            int t = __shfl_up(s, off);
            if (lane >= off) s += t;
        }
        if (i < n) {
            offs[i] = carry + s - v;
            dinv[i] = rsqrtf((float)(v + 1));
        }
        carry += __shfl(s, 63);
    }
}

__global__ void fill_csr(const int* __restrict__ src, const int* __restrict__ dst,
                         const int* __restrict__ offs, int* __restrict__ fill,
                         int* __restrict__ srcs, int E) {
    int e = blockIdx.x * 256 + threadIdx.x;
    if (e >= E) return;
    int d = dst[e];
    int p = offs[d] + atomicAdd(&fill[d], 1);
    srcs[p] = src[e];
}

// out[i][c] = relu( dinv[i] * ( sum_{s in N(i)} h[s][c]*dinv[s] + dinv[i]*h[i][c] ) + bias[c] )
__global__ void agg128(const float* __restrict__ h, const float* __restrict__ dinv,
                       const int* __restrict__ offs, const int* __restrict__ cnt,
                       const int* __restrict__ srcs, const float* __restrict__ bias,
                       float* __restrict__ out, int n) {
    int i = blockIdx.x;
    int c = threadIdx.x;
    float di = dinv[i];
    float acc = h[(size_t)i * HID + c] * di;
    int o = offs[i], e = cnt[i];
    for (int t = 0; t < e; ++t) {
        int s = srcs[o + t];
        acc += h[(size_t)s * HID + c] * dinv[s];
    }
    float v = acc * di + bias[c];
    out[(size_t)i * HID + c] = fmaxf(v, 0.f);
}

// same aggregation over the 4-wide h2, no relu
__global__ void agg4(const float* __restrict__ h2, const float* __restrict__ dinv,
                     const int* __restrict__ offs, const int* __restrict__ cnt,
                     const int* __restrict__ srcs, const float* __restrict__ b2,
                     float* __restrict__ out, int n) {
    int gid = blockIdx.x * 256 + threadIdx.x;
    int i = gid >> 2;
    int c = gid & 3;
    if (i >= n) return;
    float di = dinv[i];
    float acc = h2[(size_t)i * 4 + c] * di;
    int o = offs[i], e = cnt[i];
    for (int t = 0; t < e; ++t) {
        int s = srcs[o + t];
        acc += h2[(size_t)s * 4 + c] * dinv[s];
    }
    out[(size_t)i * 4 + c] = acc * di + b2[c];
}

extern "C" void kernel_launch(void* const* d_in, const int* in_sizes, int n_in,
                              void* d_out, int out_size, void* d_ws, size_t ws_size,
                              hipStream_t stream) {
    const float* text = (const float*)d_in[0];
    const float* mel  = (const float*)d_in[1];
    const int*   ei   = (const int*)d_in[2];
    const float* Wmel = (const float*)d_in[3];
    const float* bmel = (const float*)d_in[4];
    const float* Wcat = (const float*)d_in[5];
    const float* bcat = (const float*)d_in[6];
    const float* W1   = (const float*)d_in[7];
    const float* b1   = (const float*)d_in[8];
    const float* W2   = (const float*)d_in[9];
    const float* b2   = (const float*)d_in[10];
    float* out = (float*)d_out;

    const int n = in_sizes[0] / 768;   // 20000
    const int E = in_sizes[2] / 2;     // 640000
    const int Kmel = 16384, Kcat = 896;

    char* ws = (char*)d_ws;
    size_t off = 0;
    auto alloc = [&](size_t bytes) {
        void* p = ws + off;
        off += (bytes + 255) & ~(size_t)255;
        return p;
    };
    __bf16* Bf1 = (__bf16*)alloc((size_t)Kmel * HID * 2);
    __bf16* Bf2 = (__bf16*)alloc((size_t)Kcat * HID * 2);
    __bf16* Bf3 = (__bf16*)alloc((size_t)HID * HID * 2);
    float* m    = (float*)alloc((size_t)n * HID * 4);
    float* x    = (float*)alloc((size_t)n * HID * 4);
    float* h1   = (float*)alloc((size_t)n * HID * 4);
    float* yb   = (float*)alloc((size_t)n * HID * 4);
    float* h2   = (float*)alloc((size_t)n * 4 * 4);
    int* cnt    = (int*)alloc((size_t)n * 4);
    int* offs   = (int*)alloc((size_t)n * 4);
    int* fill   = (int*)alloc((size_t)n * 4);
    float* dinv = (float*)alloc((size_t)n * 4);
    int* srcs   = (int*)alloc((size_t)E * 4);
    (void)ws_size; (void)n_in; (void)out_size;

    const int* srcI = ei;
    const int* dstI = ei + E;

    // ---- degrees + CSR ----
    hipMemsetAsync(cnt, 0, n * 4, stream);
    hipMemsetAsync(fill, 0, n * 4, stream);
    count_dst<<<(E + 255) / 256, 256, 0, stream>>>(dstI, cnt, E);
    scan_wave<<<1, 64, 0, stream>>>(cnt, offs, dinv, n);
    fill_csr<<<(E + 255) / 256, 256, 0, stream>>>(srcI, dstI, offs, fill, srcs, E);

    // ---- pack weights to fragment-major bf16 ----
    pack_b_frag<<<(Kmel / 32 * 512 + 255) / 256, 256, 0, stream>>>(Wmel, Bf1, Kmel / 32);
    pack_b_frag<<<(Kcat / 32 * 512 + 255) / 256, 256, 0, stream>>>(Wcat, Bf2, Kcat / 32);
    pack_b_frag<<<(HID / 32 * 512 + 255) / 256, 256, 0, stream>>>(W1, Bf3, HID / 32);

    const int gblk = n / 32;  // 625 (20000 = 625*32, no tail)
    // m = relu(mel @ Wmel + bmel)
    gemm_tile<true><<<gblk, 256, 0, stream>>>(mel, Kmel, 1 << 30, nullptr, 0, Bf1, bmel, m, Kmel / 128);
    // x = relu([text | m] @ Wcat + bcat)
    gemm_tile<true><<<gblk, 256, 0, stream>>>(text, 768, 768, m, HID, Bf2, bcat, x, Kcat / 128);
    // h1 = x @ W1
    gemm_tile<false><<<gblk, 256, 0, stream>>>(x, HID, 1 << 30, nullptr, 0, Bf3, nullptr, h1, 1);
    // yb = relu(agg(h1) + b1)
    agg128<<<n, HID, 0, stream>>>(h1, dinv, offs, cnt, srcs, b1, yb, n);
    // h2 = yb @ W2
    gemm_w2<<<(n + 255) / 256, 256, 0, stream>>>(yb, W2, h2, n);
    // out = agg(h2) + b2
    agg4<<<(n * 4 + 255) / 256, 256, 0, stream>>>(h2, dinv, offs, cnt, srcs, b2, out, n);
}

// Round 3
// 764.903 us; speedup vs baseline: 1.0167x; 1.0167x over previous
//
#include <hip/hip_runtime.h>
#include <hip/hip_bf16.h>
#include <cstdint>

typedef float f32x4 __attribute__((ext_vector_type(4)));
typedef __bf16 bf16x8 __attribute__((ext_vector_type(8)));

#define HID 128

// Pack W [K][128] fp32 -> fragment-major bf16: Bf[ki][nf][lane][8]
// lane l of fragment (ki,nf) holds B[k = ki*32 + (l>>4)*8 + j][n = nf*16 + (l&15)]
__global__ void pack_b_frag(const float* __restrict__ W, __bf16* __restrict__ Bf, int kiters) {
    int idx = blockIdx.x * 256 + threadIdx.x;
    int total = kiters * 512;
    if (idx >= total) return;
    int lane = idx & 63;
    int nf = (idx >> 6) & 7;
    int ki = idx >> 9;
    int n = nf * 16 + (lane & 15);
    int kb = ki * 32 + ((lane >> 4) * 8);
    bf16x8 v;
#pragma unroll
    for (int j = 0; j < 8; ++j) v[j] = (__bf16)W[(size_t)(kb + j) * HID + n];
    *reinterpret_cast<bf16x8*>(Bf + (size_t)idx * 8) = v;
}

// m = relu(mel @ Wmel + bmel). Block = 4 waves, 32 rows, K-split x4 + LDS reduce.
template<int NITER>
__global__ __launch_bounds__(256) void gemm_mel(
    const float* __restrict__ A0, int lda0,
    const __bf16* __restrict__ Bf,
    const float* __restrict__ bias,
    float* __restrict__ out)
{
    const int tid = threadIdx.x;
    const int lane = tid & 63;
    const int w = tid >> 6;
    const int row_base = blockIdx.x * 32;
    const int rif = lane & 15;
    const int kg = lane >> 4;

    f32x4 zero = {0.f, 0.f, 0.f, 0.f};
    f32x4 acc[2][8];
#pragma unroll
    for (int i = 0; i < 2; ++i)
#pragma unroll
        for (int j = 0; j < 8; ++j) acc[i][j] = zero;

    const bf16x8* __restrict__ BfV = reinterpret_cast<const bf16x8*>(Bf);
    const int kstart = w * (NITER * 32);

#pragma unroll 4
    for (int it = 0; it < NITER; ++it) {
        const int k0 = kstart + it * 32;
        const int kc = k0 + kg * 8;
        bf16x8 af[2];
#pragma unroll
        for (int mi = 0; mi < 2; ++mi) {
            const int row = row_base + mi * 16 + rif;
            const f32x4* ap = reinterpret_cast<const f32x4*>(A0 + (size_t)row * lda0 + kc);
            f32x4 v0 = __builtin_nontemporal_load(ap);
            f32x4 v1 = __builtin_nontemporal_load(ap + 1);
            af[mi][0] = (__bf16)v0.x; af[mi][1] = (__bf16)v0.y;
            af[mi][2] = (__bf16)v0.z; af[mi][3] = (__bf16)v0.w;
            af[mi][4] = (__bf16)v1.x; af[mi][5] = (__bf16)v1.y;
            af[mi][6] = (__bf16)v1.z; af[mi][7] = (__bf16)v1.w;
        }
        const bf16x8* bp = BfV + (size_t)(k0 >> 5) * 512 + lane;
#pragma unroll
        for (int nf = 0; nf < 8; ++nf) {
            bf16x8 b = bp[nf * 64];
            acc[0][nf] = __builtin_amdgcn_mfma_f32_16x16x32_bf16(af[0], b, acc[0][nf], 0, 0, 0);
            acc[1][nf] = __builtin_amdgcn_mfma_f32_16x16x32_bf16(af[1], b, acc[1][nf], 0, 0, 0);
        }
    }

    __shared__ float red[4][32][HID];
#pragma unroll
    for (int mi = 0; mi < 2; ++mi)
#pragma unroll
        for (int nf = 0; nf < 8; ++nf)
#pragma unroll
            for (int j = 0; j < 4; ++j)
                red[w][mi * 16 + kg * 4 + j][nf * 16 + rif] = acc[mi][nf][j];
    __syncthreads();
#pragma unroll
    for (int p = 0; p < 16; ++p) {
        int idx = tid + p * 256;
        int r = idx >> 7, c = idx & 127;
        float v = red[0][r][c] + red[1][r][c] + red[2][r][c] + red[3][r][c];
        v = fmaxf(v + bias[c], 0.f);
        out[(size_t)(row_base + r) * HID + c] = v;
    }
}

// Fused: x = relu([text|m] @ Wcat + bcat)  (kept in LDS as bf16, never global)
//        h1 = x @ W1                       (written to global)
__global__ __launch_bounds__(256) void gemm_cat_h1(
    const float* __restrict__ A0,   // text [n][768]
    const float* __restrict__ A1,   // m    [n][128]
    const __bf16* __restrict__ Bf2, // Wcat packed
    const __bf16* __restrict__ Bf3, // W1 packed
    const float* __restrict__ bcat,
    float* __restrict__ h1)
{
    const int tid = threadIdx.x;
    const int lane = tid & 63;
    const int w = tid >> 6;
    const int row_base = blockIdx.x * 32;
    const int rif = lane & 15;
    const int kg = lane >> 4;

    f32x4 zero = {0.f, 0.f, 0.f, 0.f};
    f32x4 acc[2][8];
#pragma unroll
    for (int i = 0; i < 2; ++i)
#pragma unroll
        for (int j = 0; j < 8; ++j) acc[i][j] = zero;

    const bf16x8* __restrict__ Bf2V = reinterpret_cast<const bf16x8*>(Bf2);
    const int kstart = w * 224;     // 896 / 4 waves

#pragma unroll
    for (int it = 0; it < 7; ++it) {
        const int k0 = kstart + it * 32;
        const int kc = k0 + kg * 8;
        bf16x8 af[2];
#pragma unroll
        for (int mi = 0; mi < 2; ++mi) {
            const int row = row_base + mi * 16 + rif;
            const float* ap;
            if (kc < 768) ap = A0 + (size_t)row * 768 + kc;
            else          ap = A1 + (size_t)row * HID + (kc - 768);
            const f32x4* apv = reinterpret_cast<const f32x4*>(ap);
            f32x4 v0 = apv[0];
            f32x4 v1 = apv[1];
            af[mi][0] = (__bf16)v0.x; af[mi][1] = (__bf16)v0.y;
            af[mi][2] = (__bf16)v0.z; af[mi][3] = (__bf16)v0.w;
            af[mi][4] = (__bf16)v1.x; af[mi][5] = (__bf16)v1.y;
            af[mi][6] = (__bf16)v1.z; af[mi][7] = (__bf16)v1.w;
        }
        const bf16x8* bp = Bf2V + (size_t)(k0 >> 5) * 512 + lane;
#pragma unroll
        for (int nf = 0; nf < 8; ++nf) {
            bf16x8 b = bp[nf * 64];
            acc[0][nf] = __builtin_amdgcn_mfma_f32_16x16x32_bf16(af[0], b, acc[0][nf], 0, 0, 0);
            acc[1][nf] = __builtin_amdgcn_mfma_f32_16x16x32_bf16(af[1], b, acc[1][nf], 0, 0, 0);
        }
    }

    __shared__ float red[4][32][HID];
    __shared__ __bf16 xs[32][136];   // rows 272B apart: 16B-aligned, spreads banks

#pragma unroll
    for (int mi = 0; mi < 2; ++mi)
#pragma unroll
        for (int nf = 0; nf < 8; ++nf)
#pragma unroll
            for (int j = 0; j < 4; ++j)
                red[w][mi * 16 + kg * 4 + j][nf * 16 + rif] = acc[mi][nf][j];
    __syncthreads();
#pragma unroll
    for (int p = 0; p < 16; ++p) {
        int idx = tid + p * 256;
        int r = idx >> 7, c = idx & 127;
        float v = red[0][r][c] + red[1][r][c] + red[2][r][c] + red[3][r][c];
        v = fmaxf(v + bcat[c], 0.f);
        xs[r][c] = (__bf16)v;
    }
    __syncthreads();

    // stage 2: h1 = x @ W1, K=128 split as 32 per wave
    f32x4 acc2[2][8];
#pragma unroll
    for (int i = 0; i < 2; ++i)
#pragma unroll
        for (int j = 0; j < 8; ++j) acc2[i][j] = zero;

    {
        const int k0 = w * 32;
        bf16x8 af[2];
#pragma unroll
        for (int mi = 0; mi < 2; ++mi)
            af[mi] = *reinterpret_cast<const bf16x8*>(&xs[mi * 16 + rif][k0 + kg * 8]);
        const bf16x8* bp = reinterpret_cast<const bf16x8*>(Bf3) + (size_t)w * 512 + lane;
#pragma unroll
        for (int nf = 0; nf < 8; ++nf) {
            bf16x8 b = bp[nf * 64];
            acc2[0][nf] = __builtin_amdgcn_mfma_f32_16x16x32_bf16(af[0], b, acc2[0][nf], 0, 0, 0);
            acc2[1][nf] = __builtin_amdgcn_mfma_f32_16x16x32_bf16(af[1], b, acc2[1][nf], 0, 0, 0);
        }
    }

#pragma unroll
    for (int mi = 0; mi < 2; ++mi)
#pragma unroll
        for (int nf = 0; nf < 8; ++nf)
#pragma unroll
            for (int j = 0; j < 4; ++j)
                red[w][mi * 16 + kg * 4 + j][nf * 16 + rif] = acc2[mi][nf][j];
    __syncthreads();
#pragma unroll
    for (int p = 0; p < 16; ++p) {
        int idx = tid + p * 256;
        int r = idx >> 7, c = idx & 127;
        float v = red[0][r][c] + red[1][r][c] + red[2][r][c] + red[3][r][c];
        h1[(size_t)(row_base + r) * HID + c] = v;
    }
}

__global__ void count_dst(const int* __restrict__ dst, int* __restrict__ cnt, int E) {
    int e = blockIdx.x * 256 + threadIdx.x;
    if (e < E) atomicAdd(&cnt[dst[e]], 1);
}

// single-block parallel exclusive scan (1024 threads, 16 waves)
__global__ __launch_bounds__(1024) void scan_block(const int* __restrict__ cnt,
    int* __restrict__ offs, float* __restrict__ dinv, int n) {
    int tid = threadIdx.x;
    int CH = (n + 1023) >> 10;
    int s0 = tid * CH;
    int s1 = min(s0 + CH, n);
    int sum = 0;
    for (int i = s0; i < s1; ++i) sum += cnt[i];
    int lane = tid & 63, wv = tid >> 6;
    int s = sum;
#pragma unroll
    for (int off = 1; off < 64; off <<= 1) {
        int t = __shfl_up(s, off);
        if (lane >= off) s += t;
    }
    __shared__ int wsum[16];
    __shared__ int wbase[16];
    if (lane == 63) wsum[wv] = s;
    __syncthreads();
    if (tid == 0) {
        int a = 0;
#pragma unroll
        for (int k = 0; k < 16; ++k) { wbase[k] = a; a += wsum[k]; }
    }
    __syncthreads();
    int run = wbase[wv] + (s - sum);
    for (int i = s0; i < s1; ++i) {
        int v = cnt[i];
        offs[i] = run;
        dinv[i] = rsqrtf((float)(v + 1));
        run += v;
    }
}

__global__ void fill_csr(const int* __restrict__ src, const int* __restrict__ dst,
                         const int* __restrict__ offs, int* __restrict__ fill,
                         int* __restrict__ srcs, int E) {
    int e = blockIdx.x * 256 + threadIdx.x;
    if (e >= E) return;
    int d = dst[e];
    int p = offs[d] + atomicAdd(&fill[d], 1);
    srcs[p] = src[e];
}

// Fused: yb = relu(dinv_i*(sum_s h[s]*dinv[s] + dinv_i*h[i]) + b1); h2 = yb @ W2
__global__ __launch_bounds__(128) void agg_h_w2(const float* __restrict__ h,
    const float* __restrict__ dinv, const int* __restrict__ offs,
    const int* __restrict__ cnt, const int* __restrict__ srcs,
    const float* __restrict__ b1, const float* __restrict__ W2,
    float* __restrict__ h2, int n) {
    int i = blockIdx.x;
    int c = threadIdx.x;
    float di = dinv[i];
    float acc = h[(size_t)i * HID + c] * di;
    int o = offs[i], e = cnt[i];
    int t = 0;
    for (; t + 4 <= e; t += 4) {
        int a0 = srcs[o + t], a1 = srcs[o + t + 1], a2 = srcs[o + t + 2], a3 = srcs[o + t + 3];
        float d0 = dinv[a0], d1 = dinv[a1], d2 = dinv[a2], d3 = dinv[a3];
        float v0 = h[(size_t)a0 * HID + c], v1 = h[(size_t)a1 * HID + c];
        float v2 = h[(size_t)a2 * HID + c], v3 = h[(size_t)a3 * HID + c];
        acc += v0 * d0 + v1 * d1 + v2 * d2 + v3 * d3;
    }
    for (; t < e; ++t) {
        int s = srcs[o + t];
        acc += h[(size_t)s * HID + c] * dinv[s];
    }
    float yb = fmaxf(acc * di + b1[c], 0.f);
    float4 wr = *reinterpret_cast<const float4*>(W2 + c * 4);
    float p0 = yb * wr.x, p1 = yb * wr.y, p2 = yb * wr.z, p3 = yb * wr.w;
#pragma unroll
    for (int off = 32; off; off >>= 1) {
        p0 += __shfl_down(p0, off);
        p1 += __shfl_down(p1, off);
        p2 += __shfl_down(p2, off);
        p3 += __shfl_down(p3, off);
    }
    __shared__ float red[2][4];
    if ((c & 63) == 0) {
        int wv = c >> 6;
        red[wv][0] = p0; red[wv][1] = p1; red[wv][2] = p2; red[wv][3] = p3;
    }
    __syncthreads();
    if (c < 4) h2[(size_t)i * 4 + c] = red[0][c] + red[1][c];
}

// out = agg(h2) + b2 (no relu), 4 threads per node
__global__ void agg4(const float* __restrict__ h2, const float* __restrict__ dinv,
                     const int* __restrict__ offs, const int* __restrict__ cnt,
                     const int* __restrict__ srcs, const float* __restrict__ b2,
                     float* __restrict__ out, int n) {
    int gid = blockIdx.x * 256 + threadIdx.x;
    int i = gid >> 2;
    int c = gid & 3;
    if (i >= n) return;
    float di = dinv[i];
    float acc = h2[(size_t)i * 4 + c] * di;
    int o = offs[i], e = cnt[i];
    int t = 0;
    for (; t + 4 <= e; t += 4) {
        int a0 = srcs[o + t], a1 = srcs[o + t + 1], a2 = srcs[o + t + 2], a3 = srcs[o + t + 3];
        float v0 = h2[(size_t)a0 * 4 + c] * dinv[a0];
        float v1 = h2[(size_t)a1 * 4 + c] * dinv[a1];
        float v2 = h2[(size_t)a2 * 4 + c] * dinv[a2];
        float v3 = h2[(size_t)a3 * 4 + c] * dinv[a3];
        acc += v0 + v1 + v2 + v3;
    }
    for (; t < e; ++t) {
        int s = srcs[o + t];
        acc += h2[(size_t)s * 4 + c] * dinv[s];
    }
    out[(size_t)i * 4 + c] = acc * di + b2[c];
}

extern "C" void kernel_launch(void* const* d_in, const int* in_sizes, int n_in,
                              void* d_out, int out_size, void* d_ws, size_t ws_size,
                              hipStream_t stream) {
    const float* text = (const float*)d_in[0];
    const float* mel  = (const float*)d_in[1];
    const int*   ei   = (const int*)d_in[2];
    const float* Wmel = (const float*)d_in[3];
    const float* bmel = (const float*)d_in[4];
    const float* Wcat = (const float*)d_in[5];
    const float* bcat = (const float*)d_in[6];
    const float* W1   = (const float*)d_in[7];
    const float* b1   = (const float*)d_in[8];
    const float* W2   = (const float*)d_in[9];
    const float* b2   = (const float*)d_in[10];
    float* out = (float*)d_out;

    const int n = in_sizes[0] / 768;   // 20000
    const int E = in_sizes[2] / 2;     // 640000
    const int Kmel = 16384;
    const int Kcat = 896;

    char* ws = (char*)d_ws;
    size_t off = 0;
    auto alloc = [&](size_t bytes) {
        void* p = ws + off;
        off += (bytes + 255) & ~(size_t)255;
        return p;
    };
    __bf16* Bf1 = (__bf16*)alloc((size_t)Kmel * HID * 2);
    __bf16* Bf2 = (__bf16*)alloc((size_t)Kcat * HID * 2);
    __bf16* Bf3 = (__bf16*)alloc((size_t)HID * HID * 2);
    float* m    = (float*)alloc((size_t)n * HID * 4);
    float* h1   = (float*)alloc((size_t)n * HID * 4);
    float* h2   = (float*)alloc((size_t)n * 4 * 4);
    int* cnt    = (int*)alloc((size_t)n * 4);
    int* offs   = (int*)alloc((size_t)n * 4);
    int* fill   = (int*)alloc((size_t)n * 4);
    float* dinv = (float*)alloc((size_t)n * 4);
    int* srcs   = (int*)alloc((size_t)E * 4);
    (void)ws_size; (void)n_in; (void)out_size;

    const int* srcI = ei;
    const int* dstI = ei + E;

    // ---- degrees + CSR ----
    (void)hipMemsetAsync(cnt, 0, n * 4, stream);
    (void)hipMemsetAsync(fill, 0, n * 4, stream);
    count_dst<<<(E + 255) / 256, 256, 0, stream>>>(dstI, cnt, E);
    scan_block<<<1, 1024, 0, stream>>>(cnt, offs, dinv, n);
    fill_csr<<<(E + 255) / 256, 256, 0, stream>>>(srcI, dstI, offs, fill, srcs, E);

    // ---- pack weights ----
    pack_b_frag<<<(Kmel / 32 * 512 + 255) / 256, 256, 0, stream>>>(Wmel, Bf1, Kmel / 32);
    pack_b_frag<<<(Kcat / 32 * 512 + 255) / 256, 256, 0, stream>>>(Wcat, Bf2, Kcat / 32);
    pack_b_frag<<<(HID / 32 * 512 + 255) / 256, 256, 0, stream>>>(W1, Bf3, HID / 32);

    const int gblk = n / 32;  // 625
    // m = relu(mel @ Wmel + bmel)   (K split: 16384/4/32 = 128 iters/wave)
    gemm_mel<128><<<gblk, 256, 0, stream>>>(mel, Kmel, Bf1, bmel, m);
    // x = relu([text|m] @ Wcat + bcat); h1 = x @ W1   (fused)
    gemm_cat_h1<<<gblk, 256, 0, stream>>>(text, m, Bf2, Bf3, bcat, h1);
    // h2 = relu(agg(h1)+b1) @ W2    (fused)
    agg_h_w2<<<n, 128, 0, stream>>>(h1, dinv, offs, cnt, srcs, b1, W2, h2, n);
    // out = agg(h2) + b2
    agg4<<<(n * 4 + 255) / 256, 256, 0, stream>>>(h2, dinv, offs, cnt, srcs, b2, out, n);
}

// Round 4
// 519.276 us; speedup vs baseline: 1.4977x; 1.4730x over previous
//
#include <hip/hip_runtime.h>
#include <hip/hip_bf16.h>
#include <cstdint>

typedef float f32x4 __attribute__((ext_vector_type(4)));
typedef __bf16 bf16x8 __attribute__((ext_vector_type(8)));
typedef __bf16 bf16x4 __attribute__((ext_vector_type(4)));

#define HID 128

// Pack W [K][128] fp32 -> fragment-major bf16: Bf[ki][nf][lane][8]
// lane l of fragment (ki,nf) holds B[k = ki*32 + (l>>4)*8 + j][n = nf*16 + (l&15)]
__global__ void pack_b_frag(const float* __restrict__ W, __bf16* __restrict__ Bf, int kiters) {
    int idx = blockIdx.x * 256 + threadIdx.x;
    int total = kiters * 512;
    if (idx >= total) return;
    int lane = idx & 63;
    int nf = (idx >> 6) & 7;
    int ki = idx >> 9;
    int n = nf * 16 + (lane & 15);
    int kb = ki * 32 + ((lane >> 4) * 8);
    bf16x8 v;
#pragma unroll
    for (int j = 0; j < 8; ++j) v[j] = (__bf16)W[(size_t)(kb + j) * HID + n];
    *reinterpret_cast<bf16x8*>(Bf + (size_t)idx * 8) = v;
}

// m = relu(mel @ Wmel + bmel), coalesced-A version.
// Block = 256 thr (4 waves), 32 rows, K-step = 512 floats, K-split x4 across waves.
// A staged via LDS: each wave-instr reads ONE contiguous 1KB row-segment (64 lanes x 16B),
// cvt fp32->bf16 in-reg, ds_write to XOR-swizzled tile; frag reads ~2-way conflict (free).
// Epilogue red[] aliases the tile buffers (only used after K-loop) -> 64KB LDS total.
__global__ __launch_bounds__(256, 2) void gemm_mel2(
    const float* __restrict__ A0,
    const __bf16* __restrict__ Bf,
    const float* __restrict__ bias,
    float* __restrict__ out)
{
    const int tid = threadIdx.x;
    const int lane = tid & 63;
    const int wv = tid >> 6;
    const int row_base = blockIdx.x * 32;
    const int rif = lane & 15;
    const int kg = lane >> 4;

    __shared__ __align__(16) char ldsb[65536];   // [2][32 rows][1024B] bf16 tile; aliased as red[4][32][128] f32

    f32x4 zero = {0.f, 0.f, 0.f, 0.f};
    f32x4 acc[2][8];
#pragma unroll
    for (int i = 0; i < 2; ++i)
#pragma unroll
        for (int j = 0; j < 8; ++j) acc[i][j] = zero;

    const bf16x8* __restrict__ BfV = reinterpret_cast<const bf16x8*>(Bf);

    f32x4 st[16];

    // ---- staging helpers (all j compile-time; seg = wv*16+j; row = seg>>1; half = seg&1) ----
    auto stage_load = [&](int s) {
#pragma unroll
        for (int j = 0; j < 16; ++j) {
            int seg = wv * 16 + j;
            int row = seg >> 1, half = seg & 1;
            const float* gp = A0 + (size_t)(row_base + row) * 16384 + s * 512 + half * 256 + (lane << 2);
            st[j] = __builtin_nontemporal_load(reinterpret_cast<const f32x4*>(gp));
        }
    };
    auto stage_write = [&](int buf) {
#pragma unroll
        for (int j = 0; j < 16; ++j) {
            int seg = wv * 16 + j;
            int row = seg >> 1, half = seg & 1;
            int byte = row * 1024 + ((half * 512 + lane * 8) ^ ((row & 7) << 4)) + buf * 32768;
            bf16x4 v;
            v[0] = (__bf16)st[j][0]; v[1] = (__bf16)st[j][1];
            v[2] = (__bf16)st[j][2]; v[3] = (__bf16)st[j][3];
            *reinterpret_cast<bf16x4*>(ldsb + byte) = v;
        }
    };
    auto compute2 = [&](int cur, int s, int kt0) {
#pragma unroll
        for (int kt = kt0; kt < kt0 + 2; ++kt) {
            bf16x8 af[2];
#pragma unroll
            for (int mi = 0; mi < 2; ++mi) {
                int row = mi * 16 + rif;
                int byte = row * 1024 + ((wv * 256 + kt * 64 + kg * 16) ^ ((rif & 7) << 4)) + cur * 32768;
                af[mi] = *reinterpret_cast<const bf16x8*>(ldsb + byte);
            }
            int ki = s * 16 + wv * 4 + kt;
            const bf16x8* bp = BfV + (size_t)ki * 512 + lane;
#pragma unroll
            for (int nf = 0; nf < 8; ++nf) {
                bf16x8 b = bp[nf * 64];
                acc[0][nf] = __builtin_amdgcn_mfma_f32_16x16x32_bf16(af[0], b, acc[0][nf], 0, 0, 0);
                acc[1][nf] = __builtin_amdgcn_mfma_f32_16x16x32_bf16(af[1], b, acc[1][nf], 0, 0, 0);
            }
        }
    };

    // ---- main loop: 32 K-steps of 512 floats, double-buffered, 1 barrier/step ----
    stage_load(0);
    stage_write(0);
    for (int s = 0; s < 32; ++s) {
        int cur = s & 1;
        if (s + 1 < 32) stage_load(s + 1);     // HBM latency hides under compute below
        __syncthreads();                        // buf[cur] writes visible; prior reads of buf[cur^1] done
        compute2(cur, s, 0);
        compute2(cur, s, 2);
        if (s + 1 < 32) stage_write(cur ^ 1);
    }

    // ---- epilogue: cross-wave K-split reduction (red aliases the tile) ----
    __syncthreads();   // all tile reads done before alias reuse
    float* red = reinterpret_cast<float*>(ldsb);   // red[w][r][c] = [(w*32+r)*128+c]
#pragma unroll
    for (int mi = 0; mi < 2; ++mi)
#pragma unroll
        for (int nf = 0; nf < 8; ++nf)
#pragma unroll
            for (int j = 0; j < 4; ++j)
                red[(wv * 32 + mi * 16 + kg * 4 + j) * HID + nf * 16 + rif] = acc[mi][nf][j];
    __syncthreads();
#pragma unroll
    for (int p = 0; p < 16; ++p) {
        int idx = tid + p * 256;
        int r = idx >> 7, c = idx & 127;
        float v = red[r * HID + c] + red[(32 + r) * HID + c]
                + red[(64 + r) * HID + c] + red[(96 + r) * HID + c];
        v = fmaxf(v + bias[c], 0.f);
        out[(size_t)(row_base + r) * HID + c] = v;
    }
}

// Fused: x = relu([text|m] @ Wcat + bcat)  (kept in LDS as bf16, never global)
//        h1 = x @ W1                       (written to global)
__global__ __launch_bounds__(256) void gemm_cat_h1(
    const float* __restrict__ A0,   // text [n][768]
    const float* __restrict__ A1,   // m    [n][128]
    const __bf16* __restrict__ Bf2, // Wcat packed
    const __bf16* __restrict__ Bf3, // W1 packed
    const float* __restrict__ bcat,
    float* __restrict__ h1)
{
    const int tid = threadIdx.x;
    const int lane = tid & 63;
    const int w = tid >> 6;
    const int row_base = blockIdx.x * 32;
    const int rif = lane & 15;
    const int kg = lane >> 4;

    f32x4 zero = {0.f, 0.f, 0.f, 0.f};
    f32x4 acc[2][8];
#pragma unroll
    for (int i = 0; i < 2; ++i)
#pragma unroll
        for (int j = 0; j < 8; ++j) acc[i][j] = zero;

    const bf16x8* __restrict__ Bf2V = reinterpret_cast<const bf16x8*>(Bf2);
    const int kstart = w * 224;     // 896 / 4 waves

#pragma unroll
    for (int it = 0; it < 7; ++it) {
        const int k0 = kstart + it * 32;
        const int kc = k0 + kg * 8;
        bf16x8 af[2];
#pragma unroll
        for (int mi = 0; mi < 2; ++mi) {
            const int row = row_base + mi * 16 + rif;
            const float* ap;
            if (kc < 768) ap = A0 + (size_t)row * 768 + kc;
            else          ap = A1 + (size_t)row * HID + (kc - 768);
            const f32x4* apv = reinterpret_cast<const f32x4*>(ap);
            f32x4 v0 = apv[0];
            f32x4 v1 = apv[1];
            af[mi][0] = (__bf16)v0.x; af[mi][1] = (__bf16)v0.y;
            af[mi][2] = (__bf16)v0.z; af[mi][3] = (__bf16)v0.w;
            af[mi][4] = (__bf16)v1.x; af[mi][5] = (__bf16)v1.y;
            af[mi][6] = (__bf16)v1.z; af[mi][7] = (__bf16)v1.w;
        }
        const bf16x8* bp = Bf2V + (size_t)(k0 >> 5) * 512 + lane;
#pragma unroll
        for (int nf = 0; nf < 8; ++nf) {
            bf16x8 b = bp[nf * 64];
            acc[0][nf] = __builtin_amdgcn_mfma_f32_16x16x32_bf16(af[0], b, acc[0][nf], 0, 0, 0);
            acc[1][nf] = __builtin_amdgcn_mfma_f32_16x16x32_bf16(af[1], b, acc[1][nf], 0, 0, 0);
        }
    }

    __shared__ float red[4][32][HID];
    __shared__ __bf16 xs[32][136];

#pragma unroll
    for (int mi = 0; mi < 2; ++mi)
#pragma unroll
        for (int nf = 0; nf < 8; ++nf)
#pragma unroll
            for (int j = 0; j < 4; ++j)
                red[w][mi * 16 + kg * 4 + j][nf * 16 + rif] = acc[mi][nf][j];
    __syncthreads();
#pragma unroll
    for (int p = 0; p < 16; ++p) {
        int idx = tid + p * 256;
        int r = idx >> 7, c = idx & 127;
        float v = red[0][r][c] + red[1][r][c] + red[2][r][c] + red[3][r][c];
        v = fmaxf(v + bcat[c], 0.f);
        xs[r][c] = (__bf16)v;
    }
    __syncthreads();

    // stage 2: h1 = x @ W1, K=128 split as 32 per wave
    f32x4 acc2[2][8];
#pragma unroll
    for (int i = 0; i < 2; ++i)
#pragma unroll
        for (int j = 0; j < 8; ++j) acc2[i][j] = zero;

    {
        const int k0 = w * 32;
        bf16x8 af[2];
#pragma unroll
        for (int mi = 0; mi < 2; ++mi)
            af[mi] = *reinterpret_cast<const bf16x8*>(&xs[mi * 16 + rif][k0 + kg * 8]);
        const bf16x8* bp = reinterpret_cast<const bf16x8*>(Bf3) + (size_t)w * 512 + lane;
#pragma unroll
        for (int nf = 0; nf < 8; ++nf) {
            bf16x8 b = bp[nf * 64];
            acc2[0][nf] = __builtin_amdgcn_mfma_f32_16x16x32_bf16(af[0], b, acc2[0][nf], 0, 0, 0);
            acc2[1][nf] = __builtin_amdgcn_mfma_f32_16x16x32_bf16(af[1], b, acc2[1][nf], 0, 0, 0);
        }
    }

#pragma unroll
    for (int mi = 0; mi < 2; ++mi)
#pragma unroll
        for (int nf = 0; nf < 8; ++nf)
#pragma unroll
            for (int j = 0; j < 4; ++j)
                red[w][mi * 16 + kg * 4 + j][nf * 16 + rif] = acc2[mi][nf][j];
    __syncthreads();
#pragma unroll
    for (int p = 0; p < 16; ++p) {
        int idx = tid + p * 256;
        int r = idx >> 7, c = idx & 127;
        float v = red[0][r][c] + red[1][r][c] + red[2][r][c] + red[3][r][c];
        h1[(size_t)(row_base + r) * HID + c] = v;
    }
}

__global__ void count_dst(const int* __restrict__ dst, int* __restrict__ cnt, int E) {
    int e = blockIdx.x * 256 + threadIdx.x;
    if (e < E) atomicAdd(&cnt[dst[e]], 1);
}

// single-block parallel exclusive scan (1024 threads, 16 waves)
__global__ __launch_bounds__(1024) void scan_block(const int* __restrict__ cnt,
    int* __restrict__ offs, float* __restrict__ dinv, int n) {
    int tid = threadIdx.x;
    int CH = (n + 1023) >> 10;
    int s0 = tid * CH;
    int s1 = min(s0 + CH, n);
    int sum = 0;
    for (int i = s0; i < s1; ++i) sum += cnt[i];
    int lane = tid & 63, wv = tid >> 6;
    int s = sum;
#pragma unroll
    for (int off = 1; off < 64; off <<= 1) {
        int t = __shfl_up(s, off);
        if (lane >= off) s += t;
    }
    __shared__ int wsum[16];
    __shared__ int wbase[16];
    if (lane == 63) wsum[wv] = s;
    __syncthreads();
    if (tid == 0) {
        int a = 0;
#pragma unroll
        for (int k = 0; k < 16; ++k) { wbase[k] = a; a += wsum[k]; }
    }
    __syncthreads();
    int run = wbase[wv] + (s - sum);
    for (int i = s0; i < s1; ++i) {
        int v = cnt[i];
        offs[i] = run;
        dinv[i] = rsqrtf((float)(v + 1));
        run += v;
    }
}

__global__ void fill_csr(const int* __restrict__ src, const int* __restrict__ dst,
                         const int* __restrict__ offs, int* __restrict__ fill,
                         int* __restrict__ srcs, int E) {
    int e = blockIdx.x * 256 + threadIdx.x;
    if (e >= E) return;
    int d = dst[e];
    int p = offs[d] + atomicAdd(&fill[d], 1);
    srcs[p] = src[e];
}

// Fused: yb = relu(dinv_i*(sum_s h[s]*dinv[s] + dinv_i*h[i]) + b1); h2 = yb @ W2
__global__ __launch_bounds__(128) void agg_h_w2(const float* __restrict__ h,
    const float* __restrict__ dinv, const int* __restrict__ offs,
    const int* __restrict__ cnt, const int* __restrict__ srcs,
    const float* __restrict__ b1, const float* __restrict__ W2,
    float* __restrict__ h2, int n) {
    int i = blockIdx.x;
    int c = threadIdx.x;
    float di = dinv[i];
    float acc = h[(size_t)i * HID + c] * di;
    int o = offs[i], e = cnt[i];
    int t = 0;
    for (; t + 4 <= e; t += 4) {
        int a0 = srcs[o + t], a1 = srcs[o + t + 1], a2 = srcs[o + t + 2], a3 = srcs[o + t + 3];
        float d0 = dinv[a0], d1 = dinv[a1], d2 = dinv[a2], d3 = dinv[a3];
        float v0 = h[(size_t)a0 * HID + c], v1 = h[(size_t)a1 * HID + c];
        float v2 = h[(size_t)a2 * HID + c], v3 = h[(size_t)a3 * HID + c];
        acc += v0 * d0 + v1 * d1 + v2 * d2 + v3 * d3;
    }
    for (; t < e; ++t) {
        int s = srcs[o + t];
        acc += h[(size_t)s * HID + c] * dinv[s];
    }
    float yb = fmaxf(acc * di + b1[c], 0.f);
    float4 wr = *reinterpret_cast<const float4*>(W2 + c * 4);
    float p0 = yb * wr.x, p1 = yb * wr.y, p2 = yb * wr.z, p3 = yb * wr.w;
#pragma unroll
    for (int off = 32; off; off >>= 1) {
        p0 += __shfl_down(p0, off);
        p1 += __shfl_down(p1, off);
        p2 += __shfl_down(p2, off);
        p3 += __shfl_down(p3, off);
    }
    __shared__ float red[2][4];
    if ((c & 63) == 0) {
        int wv = c >> 6;
        red[wv][0] = p0; red[wv][1] = p1; red[wv][2] = p2; red[wv][3] = p3;
    }
    __syncthreads();
    if (c < 4) h2[(size_t)i * 4 + c] = red[0][c] + red[1][c];
}

// out = agg(h2) + b2 (no relu), 4 threads per node
__global__ void agg4(const float* __restrict__ h2, const float* __restrict__ dinv,
                     const int* __restrict__ offs, const int* __restrict__ cnt,
                     const int* __restrict__ srcs, const float* __restrict__ b2,
                     float* __restrict__ out, int n) {
    int gid = blockIdx.x * 256 + threadIdx.x;
    int i = gid >> 2;
    int c = gid & 3;
    if (i >= n) return;
    float di = dinv[i];
    float acc = h2[(size_t)i * 4 + c] * di;
    int o = offs[i], e = cnt[i];
    int t = 0;
    for (; t + 4 <= e; t += 4) {
        int a0 = srcs[o + t], a1 = srcs[o + t + 1], a2 = srcs[o + t + 2], a3 = srcs[o + t + 3];
        float v0 = h2[(size_t)a0 * 4 + c] * dinv[a0];
        float v1 = h2[(size_t)a1 * 4 + c] * dinv[a1];
        float v2 = h2[(size_t)a2 * 4 + c] * dinv[a2];
        float v3 = h2[(size_t)a3 * 4 + c] * dinv[a3];
        acc += v0 + v1 + v2 + v3;
    }
    for (; t < e; ++t) {
        int s = srcs[o + t];
        acc += h2[(size_t)s * 4 + c] * dinv[s];
    }
    out[(size_t)i * 4 + c] = acc * di + b2[c];
}

extern "C" void kernel_launch(void* const* d_in, const int* in_sizes, int n_in,
                              void* d_out, int out_size, void* d_ws, size_t ws_size,
                              hipStream_t stream) {
    const float* text = (const float*)d_in[0];
    const float* mel  = (const float*)d_in[1];
    const int*   ei   = (const int*)d_in[2];
    const float* Wmel = (const float*)d_in[3];
    const float* bmel = (const float*)d_in[4];
    const float* Wcat = (const float*)d_in[5];
    const float* bcat = (const float*)d_in[6];
    const float* W1   = (const float*)d_in[7];
    const float* b1   = (const float*)d_in[8];
    const float* W2   = (const float*)d_in[9];
    const float* b2   = (const float*)d_in[10];
    float* out = (float*)d_out;

    const int n = in_sizes[0] / 768;   // 20000
    const int E = in_sizes[2] / 2;     // 640000
    const int Kmel = 16384;
    const int Kcat = 896;

    char* ws = (char*)d_ws;
    size_t off = 0;
    auto alloc = [&](size_t bytes) {
        void* p = ws + off;
        off += (bytes + 255) & ~(size_t)255;
        return p;
    };
    __bf16* Bf1 = (__bf16*)alloc((size_t)Kmel * HID * 2);
    __bf16* Bf2 = (__bf16*)alloc((size_t)Kcat * HID * 2);
    __bf16* Bf3 = (__bf16*)alloc((size_t)HID * HID * 2);
    float* m    = (float*)alloc((size_t)n * HID * 4);
    float* h1   = (float*)alloc((size_t)n * HID * 4);
    float* h2   = (float*)alloc((size_t)n * 4 * 4);
    int* cnt    = (int*)alloc((size_t)n * 4);
    int* offs   = (int*)alloc((size_t)n * 4);
    int* fill   = (int*)alloc((size_t)n * 4);
    float* dinv = (float*)alloc((size_t)n * 4);
    int* srcs   = (int*)alloc((size_t)E * 4);
    (void)ws_size; (void)n_in; (void)out_size;

    const int* srcI = ei;
    const int* dstI = ei + E;

    // ---- degrees + CSR ----
    (void)hipMemsetAsync(cnt, 0, n * 4, stream);
    (void)hipMemsetAsync(fill, 0, n * 4, stream);
    count_dst<<<(E + 255) / 256, 256, 0, stream>>>(dstI, cnt, E);
    scan_block<<<1, 1024, 0, stream>>>(cnt, offs, dinv, n);
    fill_csr<<<(E + 255) / 256, 256, 0, stream>>>(srcI, dstI, offs, fill, srcs, E);

    // ---- pack weights ----
    pack_b_frag<<<(Kmel / 32 * 512 + 255) / 256, 256, 0, stream>>>(Wmel, Bf1, Kmel / 32);
    pack_b_frag<<<(Kcat / 32 * 512 + 255) / 256, 256, 0, stream>>>(Wcat, Bf2, Kcat / 32);
    pack_b_frag<<<(HID / 32 * 512 + 255) / 256, 256, 0, stream>>>(W1, Bf3, HID / 32);

    const int gblk = n / 32;  // 625
    // m = relu(mel @ Wmel + bmel)  -- coalesced LDS-staged version
    gemm_mel2<<<gblk, 256, 0, stream>>>(mel, Bf1, bmel, m);
    // x = relu([text|m] @ Wcat + bcat); h1 = x @ W1   (fused)
    gemm_cat_h1<<<gblk, 256, 0, stream>>>(text, m, Bf2, Bf3, bcat, h1);
    // h2 = relu(agg(h1)+b1) @ W2    (fused)
    agg_h_w2<<<n, 128, 0, stream>>>(h1, dinv, offs, cnt, srcs, b1, W2, h2, n);
    // out = agg(h2) + b2
    agg4<<<(n * 4 + 255) / 256, 256, 0, stream>>>(h2, dinv, offs, cnt, srcs, b2, out, n);
}